// Round 6
// baseline (711.969 us; speedup 1.0000x reference)
//
#include <hip/hip_runtime.h>
#include <math.h>

#define DD 1024   // hidden dim
#define HH 1408   // moe inter dim
#define NE 8      // experts

typedef __attribute__((ext_vector_type(8))) __bf16 bf16x8;
typedef __attribute__((ext_vector_type(4))) float f32x4;

__device__ __forceinline__ float bf2f(unsigned short u) {
  union { unsigned int i; float f; } v; v.i = ((unsigned int)u) << 16; return v.f;
}
__device__ __forceinline__ unsigned short f2bf(float f) {
  union { float f; unsigned int i; } v; v.f = f;
  unsigned int r = v.i + 0x7FFFu + ((v.i >> 16) & 1u);  // RNE
  return (unsigned short)(r >> 16);
}
__device__ __forceinline__ float tof(float f) { return f; }
__device__ __forceinline__ float tof(unsigned short u) { return bf2f(u); }

// load 8 consecutive elements as packed bf16[8]
__device__ __forceinline__ void ld8bf(const unsigned short* p, unsigned short* o) {
  *(uint4*)o = *(const uint4*)p;
}
__device__ __forceinline__ void ld8bf(const float* p, unsigned short* o) {
  float4 a = *(const float4*)p;
  float4 b = *(const float4*)(p + 4);
  o[0] = f2bf(a.x); o[1] = f2bf(a.y); o[2] = f2bf(a.z); o[3] = f2bf(a.w);
  o[4] = f2bf(b.x); o[5] = f2bf(b.y); o[6] = f2bf(b.z); o[7] = f2bf(b.w);
}

// ---------------- sniff input dtype: 1 = fp32, 0 = bf16 ----------------
__global__ void sniff_kernel(const unsigned short* __restrict__ xw,
                             int* __restrict__ dflag) {
  __shared__ int cnt;
  if (threadIdx.x == 0) cnt = 0;
  __syncthreads();
  unsigned short v = xw[threadIdx.x];
  int e = (v >> 7) & 0xFF;
  if (e >= 100 && e <= 140) atomicAdd(&cnt, 1);
  __syncthreads();
  if (threadIdx.x == 0) dflag[0] = (cnt < 230) ? 1 : 0;
}

// ---------------- init: zero counters ----------------
__global__ void init_kernel(int* meta) {
  if (threadIdx.x < 32) meta[threadIdx.x] = 0;
}

// ---------------- gate: one wave per token ----------------
template <class T>
__device__ void gate_body(const T* __restrict__ x,
                          const T* __restrict__ gw,
                          const T* __restrict__ gb,
                          int* __restrict__ meta,
                          int* __restrict__ tok_eidx,
                          float* __restrict__ tok_w, int t0, int TS) {
  int tl = (int)((blockIdx.x * blockDim.x + threadIdx.x) >> 6);
  int lane = threadIdx.x & 63;
  if (tl >= TS) return;
  int t = t0 + tl;
  const T* xr = x + (size_t)t * DD;
  float acc[NE];
#pragma unroll
  for (int e = 0; e < NE; e++) acc[e] = 0.f;
  for (int i = lane; i < DD; i += 64) {
    float xv = tof(xr[i]);
#pragma unroll
    for (int e = 0; e < NE; e++) acc[e] += xv * tof(gw[e * DD + i]);
  }
#pragma unroll
  for (int off = 32; off > 0; off >>= 1) {
#pragma unroll
    for (int e = 0; e < NE; e++) acc[e] += __shfl_xor(acc[e], off);
  }
  if (lane == 0) {
    float mx = acc[0];
#pragma unroll
    for (int e = 1; e < NE; e++) mx = fmaxf(mx, acc[e]);
    float s = 0.f, sc[NE], bi[NE];
#pragma unroll
    for (int e = 0; e < NE; e++) { sc[e] = expf(acc[e] - mx); s += sc[e]; }
    float inv = 1.f / s;
#pragma unroll
    for (int e = 0; e < NE; e++) { sc[e] *= inv; bi[e] = sc[e] + tof(gb[e]); }
    int i1 = 0;
#pragma unroll
    for (int e = 1; e < NE; e++) if (bi[e] > bi[i1]) i1 = e;
    int i2 = (i1 == 0) ? 1 : 0;
#pragma unroll
    for (int e = 0; e < NE; e++) if (e != i1 && bi[e] > bi[i2]) i2 = e;
    tok_eidx[t * 2] = i1; tok_eidx[t * 2 + 1] = i2;
    tok_w[t * 2] = sc[i1]; tok_w[t * 2 + 1] = sc[i2];
    atomicAdd(&meta[i1], 1);
    atomicAdd(&meta[i2], 1);
  }
}

__global__ void gate_kernel(const void* x, const void* gw, const void* gb,
                            const int* __restrict__ dflag,
                            int* meta, int* tok_eidx, float* tok_w,
                            int t0, int TS) {
  if (dflag[0])
    gate_body<float>((const float*)x, (const float*)gw, (const float*)gb,
                     meta, tok_eidx, tok_w, t0, TS);
  else
    gate_body<unsigned short>((const unsigned short*)x, (const unsigned short*)gw,
                              (const unsigned short*)gb, meta, tok_eidx, tok_w, t0, TS);
}

// ---------------- scan ----------------
__global__ void scan_kernel(int* meta) {
  if (threadIdx.x == 0 && blockIdx.x == 0) {
    int s = 0;
#pragma unroll
    for (int e = 0; e < NE; e++) {
      meta[16 + e] = s;
      meta[8 + e] = s;
      s += meta[e];
    }
    meta[16 + NE] = s;
  }
}

// ---------------- scatter ----------------
__global__ void scatter_kernel(const int* __restrict__ tok_eidx,
                               const float* __restrict__ tok_w,
                               int* __restrict__ meta,
                               int* __restrict__ rows_tok,
                               float* __restrict__ rows_wgt, int t0, int TS) {
  int tl = blockIdx.x * blockDim.x + threadIdx.x;
  if (tl >= TS) return;
  int t = t0 + tl;
#pragma unroll
  for (int k = 0; k < 2; k++) {
    int e = tok_eidx[t * 2 + k];
    int pos = atomicAdd(&meta[8 + e], 1);
    rows_tok[pos] = t;
    rows_wgt[pos] = tok_w[t * 2 + k];
  }
}

// ---------------- zero fp32 accumulator ----------------
__global__ void zero_kernel(float4* __restrict__ p, int n4) {
  int i = blockIdx.x * blockDim.x + threadIdx.x;
  int st = gridDim.x * blockDim.x;
  float4 z; z.x = z.y = z.z = z.w = 0.f;
  for (; i < n4; i += st) p[i] = z;
}

// ---------------- up-projection body (MFMA 128x128 tile, BK=32) ----------------
template <class T>
__device__ void up_body(const T* __restrict__ x,
                        const T* __restrict__ w1, const T* __restrict__ w3,
                        const T* __restrict__ b1, const T* __restrict__ b3,
                        const T* __restrict__ sw1, const T* __restrict__ sw3,
                        const T* __restrict__ sb1, const T* __restrict__ sb3,
                        const int* __restrict__ meta,
                        const int* __restrict__ rows_tok,
                        unsigned short* __restrict__ h_buf,
                        unsigned short* __restrict__ sh_buf,
                        int t0, int TS) {
  const int z = blockIdx.z;
  const bool sh = (z == NE);
  int g0, cnt;
  const T *wa, *wb, *ba, *bb;
  unsigned short* ho;
  if (sh) {
    g0 = 0; cnt = TS; wa = sw1; wb = sw3; ba = sb1; bb = sb3; ho = sh_buf;
  } else {
    g0 = meta[16 + z]; cnt = meta[17 + z] - g0;
    wa = w1 + (size_t)z * DD * HH; wb = w3 + (size_t)z * DD * HH;
    ba = b1 + (size_t)z * HH;      bb = b3 + (size_t)z * HH;
    ho = h_buf + (size_t)g0 * HH;
  }
  const int mtile = blockIdx.y;
  if (mtile * 128 >= cnt) return;
  const int n0 = blockIdx.x * 128;

  __shared__ alignas(16) unsigned short lds_a[128 * 40];
  __shared__ alignas(16) unsigned short lds_b1[128 * 40];
  __shared__ alignas(16) unsigned short lds_b3[128 * 40];

  const int tid = threadIdx.x;

  size_t abase[2];
  int aoff[2];
#pragma unroll
  for (int p = 0; p < 2; p++) {
    int idx = p * 256 + tid;
    int row = idx >> 2, c = (idx & 3) << 3;
    int m = mtile * 128 + row;
    int srow;
    if (sh) srow = t0 + ((m < cnt) ? m : (cnt - 1));
    else { int r = (m < cnt) ? m : (cnt - 1); srow = rows_tok[g0 + r]; }
    abase[p] = (size_t)srow * DD + c;
    aoff[p] = row * 40 + c;
  }
  const int kk2 = (tid >> 4) << 1;
  const int n8 = (tid & 15) << 3;
  int ii[8], boff[8];
#pragma unroll
  for (int j = 0; j < 8; j++) {
    int i = (j + (tid & 7)) & 7;
    ii[j] = i;
    boff[j] = (n8 + i) * 40 + kk2;
  }
  const size_t bcol = (size_t)(n0 + n8);

  const int wid = tid >> 6;
  const int wrow = (wid >> 1) << 6, wcol = (wid & 1) << 6;
  const int ln15 = tid & 15;
  const int kq8 = ((tid & 63) >> 4) << 3;

  f32x4 acc1[4][4], acc3[4][4];
#pragma unroll
  for (int a = 0; a < 4; a++)
#pragma unroll
    for (int b = 0; b < 4; b++) {
      acc1[a][b] = {0.f, 0.f, 0.f, 0.f};
      acc3[a][b] = {0.f, 0.f, 0.f, 0.f};
    }

  for (int k0 = 0; k0 < DD; k0 += 32) {
    __syncthreads();
#pragma unroll
    for (int p = 0; p < 2; p++) {
      unsigned short tmp[8];
      ld8bf(x + abase[p] + k0, tmp);
      *(uint4*)&lds_a[aoff[p]] = *(uint4*)tmp;
    }
    {
      unsigned short u0[8], u1[8];
      ld8bf(wa + (size_t)(k0 + kk2) * HH + bcol, u0);
      ld8bf(wa + (size_t)(k0 + kk2 + 1) * HH + bcol, u1);
#pragma unroll
      for (int j = 0; j < 8; j++) {
        int i = ii[j];
        *(unsigned int*)&lds_b1[boff[j]] =
            (unsigned int)u0[i] | ((unsigned int)u1[i] << 16);
      }
      ld8bf(wb + (size_t)(k0 + kk2) * HH + bcol, u0);
      ld8bf(wb + (size_t)(k0 + kk2 + 1) * HH + bcol, u1);
#pragma unroll
      for (int j = 0; j < 8; j++) {
        int i = ii[j];
        *(unsigned int*)&lds_b3[boff[j]] =
            (unsigned int)u0[i] | ((unsigned int)u1[i] << 16);
      }
    }
    __syncthreads();
    bf16x8 af[4];
#pragma unroll
    for (int fm = 0; fm < 4; fm++)
      af[fm] = *(const bf16x8*)&lds_a[(wrow + fm * 16 + ln15) * 40 + kq8];
#pragma unroll
    for (int fn = 0; fn < 4; fn++) {
      bf16x8 bv1 = *(const bf16x8*)&lds_b1[(wcol + fn * 16 + ln15) * 40 + kq8];
      bf16x8 bv3 = *(const bf16x8*)&lds_b3[(wcol + fn * 16 + ln15) * 40 + kq8];
#pragma unroll
      for (int fm = 0; fm < 4; fm++) {
        acc1[fm][fn] = __builtin_amdgcn_mfma_f32_16x16x32_bf16(af[fm], bv1, acc1[fm][fn], 0, 0, 0);
        acc3[fm][fn] = __builtin_amdgcn_mfma_f32_16x16x32_bf16(af[fm], bv3, acc3[fm][fn], 0, 0, 0);
      }
    }
  }

  const int kq4 = ((tid & 63) >> 4) << 2;
#pragma unroll
  for (int fm = 0; fm < 4; fm++) {
#pragma unroll
    for (int r = 0; r < 4; r++) {
      int m = mtile * 128 + wrow + fm * 16 + kq4 + r;
      if (m < cnt) {
        unsigned short* orow = ho + (size_t)m * HH + n0;
#pragma unroll
        for (int fn = 0; fn < 4; fn++) {
          int nc = wcol + fn * 16 + ln15;
          float g1 = acc1[fm][fn][r] + tof(ba[n0 + nc]);
          float g3 = acc3[fm][fn][r] + tof(bb[n0 + nc]);
          float u = g1 * g3;
          float hv = u / (1.f + expf(-u));  // silu(g1*g3)
          orow[nc] = f2bf(hv);
        }
      }
    }
  }
}

__global__ __launch_bounds__(256, 2)
void ffn_up_kernel(const void* x, const void* w1, const void* w3,
                   const void* b1, const void* b3,
                   const void* sw1, const void* sw3,
                   const void* sb1, const void* sb3,
                   const int* __restrict__ dflag,
                   const int* meta, const int* rows_tok,
                   unsigned short* h_buf, unsigned short* sh_buf,
                   int t0, int TS) {
  if (dflag[0])
    up_body<float>((const float*)x, (const float*)w1, (const float*)w3,
                   (const float*)b1, (const float*)b3, (const float*)sw1,
                   (const float*)sw3, (const float*)sb1, (const float*)sb3,
                   meta, rows_tok, h_buf, sh_buf, t0, TS);
  else
    up_body<unsigned short>((const unsigned short*)x, (const unsigned short*)w1,
                            (const unsigned short*)w3, (const unsigned short*)b1,
                            (const unsigned short*)b3, (const unsigned short*)sw1,
                            (const unsigned short*)sw3, (const unsigned short*)sb1,
                            (const unsigned short*)sb3,
                            meta, rows_tok, h_buf, sh_buf, t0, TS);
}

// ---------------- down-projection body ----------------
template <class T>
__device__ void down_body(const unsigned short* __restrict__ h_buf,
                          const unsigned short* __restrict__ sh_buf,
                          const T* __restrict__ w2, const T* __restrict__ b2,
                          const T* __restrict__ sw2, const T* __restrict__ sb2,
                          const int* __restrict__ meta,
                          const int* __restrict__ rows_tok,
                          const float* __restrict__ rows_wgt,
                          float* __restrict__ yacc,
                          int t0, int TS) {
  const int z = blockIdx.z;
  const bool sh = (z == NE);
  int g0, cnt;
  const T *wsrc, *bsrc;
  const unsigned short* hb;
  if (sh) { g0 = 0; cnt = TS; wsrc = sw2; bsrc = sb2; hb = sh_buf; }
  else {
    g0 = meta[16 + z]; cnt = meta[17 + z] - g0;
    wsrc = w2 + (size_t)z * HH * DD; bsrc = b2 + (size_t)z * DD;
    hb = h_buf + (size_t)g0 * HH;
  }
  const int mtile = blockIdx.y;
  if (mtile * 128 >= cnt) return;
  const int n0 = blockIdx.x * 128;

  __shared__ alignas(16) unsigned short lds_a[128 * 40];
  __shared__ alignas(16) unsigned short lds_b[128 * 40];

  const int tid = threadIdx.x;
  const unsigned short* asrc[2];
  int aoff[2];
#pragma unroll
  for (int p = 0; p < 2; p++) {
    int idx = p * 256 + tid;
    int row = idx >> 2, c = (idx & 3) << 3;
    int m = mtile * 128 + row;
    int r = (m < cnt) ? m : (cnt - 1);
    asrc[p] = hb + (size_t)r * HH + c;
    aoff[p] = row * 40 + c;
  }
  const int kk2 = (tid >> 4) << 1;
  const int n8 = (tid & 15) << 3;
  int ii[8], boff[8];
#pragma unroll
  for (int j = 0; j < 8; j++) {
    int i = (j + (tid & 7)) & 7;
    ii[j] = i;
    boff[j] = (n8 + i) * 40 + kk2;
  }
  const size_t bcol = (size_t)(n0 + n8);

  const int wid = tid >> 6;
  const int wrow = (wid >> 1) << 6, wcol = (wid & 1) << 6;
  const int ln15 = tid & 15;
  const int kq8 = ((tid & 63) >> 4) << 3;

  f32x4 acc[4][4];
#pragma unroll
  for (int a = 0; a < 4; a++)
#pragma unroll
    for (int b = 0; b < 4; b++) acc[a][b] = {0.f, 0.f, 0.f, 0.f};

  for (int k0 = 0; k0 < HH; k0 += 32) {
    __syncthreads();
#pragma unroll
    for (int p = 0; p < 2; p++)
      *(uint4*)&lds_a[aoff[p]] = *(const uint4*)(asrc[p] + k0);
    {
      unsigned short u0[8], u1[8];
      ld8bf(wsrc + (size_t)(k0 + kk2) * DD + bcol, u0);
      ld8bf(wsrc + (size_t)(k0 + kk2 + 1) * DD + bcol, u1);
#pragma unroll
      for (int j = 0; j < 8; j++) {
        int i = ii[j];
        *(unsigned int*)&lds_b[boff[j]] =
            (unsigned int)u0[i] | ((unsigned int)u1[i] << 16);
      }
    }
    __syncthreads();
    bf16x8 af[4];
#pragma unroll
    for (int fm = 0; fm < 4; fm++)
      af[fm] = *(const bf16x8*)&lds_a[(wrow + fm * 16 + ln15) * 40 + kq8];
#pragma unroll
    for (int fn = 0; fn < 4; fn++) {
      bf16x8 bv = *(const bf16x8*)&lds_b[(wcol + fn * 16 + ln15) * 40 + kq8];
#pragma unroll
      for (int fm = 0; fm < 4; fm++)
        acc[fm][fn] = __builtin_amdgcn_mfma_f32_16x16x32_bf16(af[fm], bv, acc[fm][fn], 0, 0, 0);
    }
  }

  const int kq4 = ((tid & 63) >> 4) << 2;
#pragma unroll
  for (int fm = 0; fm < 4; fm++) {
#pragma unroll
    for (int r = 0; r < 4; r++) {
      int m = mtile * 128 + wrow + fm * 16 + kq4 + r;
      if (m < cnt) {
        int tl; float wgt;
        if (sh) { tl = m; wgt = 1.f; }
        else { tl = rows_tok[g0 + m] - t0; wgt = rows_wgt[g0 + m]; }
        float* orow = yacc + (size_t)tl * DD + n0;
#pragma unroll
        for (int fn = 0; fn < 4; fn++) {
          int nc = wcol + fn * 16 + ln15;
          float v = wgt * (acc[fm][fn][r] + tof(bsrc[n0 + nc]));
          atomicAdd(&orow[nc], v);
        }
      }
    }
  }
}

__global__ __launch_bounds__(256, 2)
void ffn_down_kernel(const unsigned short* h_buf, const unsigned short* sh_buf,
                     const void* w2, const void* b2,
                     const void* sw2, const void* sb2,
                     const int* __restrict__ dflag,
                     const int* meta, const int* rows_tok, const float* rows_wgt,
                     float* yacc, int t0, int TS) {
  if (dflag[0])
    down_body<float>(h_buf, sh_buf, (const float*)w2, (const float*)b2,
                     (const float*)sw2, (const float*)sb2,
                     meta, rows_tok, rows_wgt, yacc, t0, TS);
  else
    down_body<unsigned short>(h_buf, sh_buf, (const unsigned short*)w2,
                              (const unsigned short*)b2, (const unsigned short*)sw2,
                              (const unsigned short*)sb2,
                              meta, rows_tok, rows_wgt, yacc, t0, TS);
}

// ---------------- finalize: fp32 accumulator -> FP32 out ----------------
__global__ void finalize_kernel(const float4* __restrict__ yacc,
                                float4* __restrict__ out, int n4) {
  int i = blockIdx.x * blockDim.x + threadIdx.x;
  int st = gridDim.x * blockDim.x;
  for (; i < n4; i += st) out[i] = yacc[i];
}

extern "C" void kernel_launch(void* const* d_in, const int* in_sizes, int n_in,
                              void* d_out, int out_size, void* d_ws, size_t ws_size,
                              hipStream_t stream) {
  const void* x   = d_in[0];
  const void* gw  = d_in[1];
  const void* gb  = d_in[2];
  const void* w1  = d_in[3];
  const void* b1  = d_in[4];
  const void* w3  = d_in[5];
  const void* b3  = d_in[6];
  const void* w2  = d_in[7];
  const void* b2  = d_in[8];
  const void* sw1 = d_in[9];
  const void* sb1 = d_in[10];
  const void* sw3 = d_in[11];
  const void* sb3 = d_in[12];
  const void* sw2 = d_in[13];
  const void* sb2 = d_in[14];

  const int T = in_sizes[0] / DD;  // 4096
  (void)n_in; (void)out_size;

  auto need = [&](int S) -> size_t {
    int TS = T / S;
    size_t o = 0;
    auto pad = [&](size_t b) { o = (o + b + 255) & ~(size_t)255; };
    pad(256);                                 // dflag
    pad(32 * sizeof(int));                    // meta
    pad((size_t)T * 2 * sizeof(int));         // tok_eidx
    pad((size_t)T * 2 * sizeof(float));       // tok_w
    pad((size_t)TS * 2 * sizeof(int));        // rows_tok
    pad((size_t)TS * 2 * sizeof(float));      // rows_wgt
    pad((size_t)TS * 2 * HH * 2);             // h_buf
    pad((size_t)TS * HH * 2);                 // sh_buf
    pad((size_t)TS * DD * sizeof(float));     // yacc
    return o;
  };
  int S = 32;
  {
    const int cand[6] = {1, 2, 4, 8, 16, 32};
    for (int ci = 0; ci < 6; ci++) {
      if (need(cand[ci]) <= ws_size) { S = cand[ci]; break; }
    }
  }
  const int TS = T / S;
  const int mt = TS / 128;

  char* w = (char*)d_ws;
  size_t off = 0;
  auto take = [&](size_t bytes) {
    char* p = w + off;
    off = (off + bytes + 255) & ~(size_t)255;
    return p;
  };
  int*   dflag    = (int*)  take(256);
  int*   meta     = (int*)  take(32 * sizeof(int));
  int*   tok_eidx = (int*)  take((size_t)T * 2 * sizeof(int));
  float* tok_w    = (float*)take((size_t)T * 2 * sizeof(float));
  int*   rows_tok = (int*)  take((size_t)TS * 2 * sizeof(int));
  float* rows_wgt = (float*)take((size_t)TS * 2 * sizeof(float));
  unsigned short* h_buf  = (unsigned short*)take((size_t)TS * 2 * HH * 2);
  unsigned short* sh_buf = (unsigned short*)take((size_t)TS * HH * 2);
  float* yacc = (float*)take((size_t)TS * DD * sizeof(float));

  sniff_kernel<<<1, 256, 0, stream>>>((const unsigned short*)x, dflag);

  for (int s = 0; s < S; s++) {
    const int t0 = s * TS;
    init_kernel<<<1, 64, 0, stream>>>(meta);
    gate_kernel<<<(TS + 3) / 4, 256, 0, stream>>>(x, gw, gb, dflag, meta, tok_eidx, tok_w, t0, TS);
    scan_kernel<<<1, 64, 0, stream>>>(meta);
    scatter_kernel<<<(TS + 255) / 256, 256, 0, stream>>>(tok_eidx, tok_w, meta, rows_tok, rows_wgt, t0, TS);
    zero_kernel<<<1024, 256, 0, stream>>>((float4*)yacc, TS * DD / 4);
    ffn_up_kernel<<<dim3(HH / 128, mt, NE + 1), 256, 0, stream>>>(
        x, w1, w3, b1, b3, sw1, sw3, sb1, sb3, dflag, meta, rows_tok, h_buf, sh_buf, t0, TS);
    ffn_down_kernel<<<dim3(DD / 128, mt, NE + 1), 256, 0, stream>>>(
        h_buf, sh_buf, w2, b2, sw2, sb2, dflag, meta, rows_tok, rows_wgt, yacc, t0, TS);
    finalize_kernel<<<1024, 256, 0, stream>>>((const float4*)yacc,
                                              (float4*)d_out + (size_t)t0 * DD / 4, TS * DD / 4);
  }
}